// Round 8
// baseline (939.087 us; speedup 1.0000x reference)
//
#include <hip/hip_runtime.h>
#include <hip/hip_bf16.h>
#include <math.h>

#define N_NODES 20000
#define N_EDGES 320000
#define NODE_DIM 64
#define EDGE_DIM 32
#define HID 128
#define HEADS 4
#define HC1 512   // HEADS*HID
#define NEG_SLOPE 0.2f

__device__ __forceinline__ unsigned short f2b(float f) {
  unsigned u = __float_as_uint(f);
  unsigned r = (u + 0x7fffu + ((u >> 16) & 1u)) >> 16;
  return (unsigned short)r;
}
__device__ __forceinline__ float b2f(unsigned short b) {
  return __uint_as_float(((unsigned)b) << 16);
}

// ---------------- CSR build ----------------
__global__ void zero_deg_kernel(int* deg) {
  int i = blockIdx.x * blockDim.x + threadIdx.x;
  if (i < N_NODES) deg[i] = 0;
}

__global__ void deg_count_kernel(const int* __restrict__ dsts, int* __restrict__ deg) {
  int e = blockIdx.x * blockDim.x + threadIdx.x;
  if (e < N_EDGES) atomicAdd(&deg[dsts[e]], 1);
}

__global__ __launch_bounds__(1024) void scan_kernel(
    const int* __restrict__ deg, int* __restrict__ offs, int* __restrict__ cursor)
{
  __shared__ int part[1024];
  int t = threadIdx.x;
  const int C = 20;                 // 1024*20 = 20480 >= N_NODES
  int base = t * C;
  int loc[C]; int s = 0;
  #pragma unroll
  for (int i = 0; i < C; i++) { loc[i] = s; int idx = base + i; s += (idx < N_NODES) ? deg[idx] : 0; }
  part[t] = s;
  __syncthreads();
  for (int off = 1; off < 1024; off <<= 1) {
    int v = (t >= off) ? part[t - off] : 0;
    __syncthreads();
    part[t] += v;
    __syncthreads();
  }
  int pbase = (t > 0) ? part[t - 1] : 0;
  #pragma unroll
  for (int i = 0; i < C; i++) {
    int idx = base + i;
    if (idx < N_NODES) { int o = pbase + loc[i]; offs[idx] = o; cursor[idx] = o; }
  }
  if (t == 1023) offs[N_NODES] = part[1023];
}

__global__ void scatter_kernel(const int* __restrict__ dsts, int* __restrict__ cursor,
                               int* __restrict__ csr) {
  int e = blockIdx.x * blockDim.x + threadIdx.x;
  if (e >= N_EDGES) return;
  int pos = atomicAdd(&cursor[dsts[e]], 1);
  csr[pos] = e;
}

// ---------------- linear1 ----------------
__global__ __launch_bounds__(256) void linear1_kernel(
    const float* __restrict__ x, const float* __restrict__ Wl,
    const float* __restrict__ bl, const float* __restrict__ Wr,
    const float* __restrict__ br, float* __restrict__ xl, float* __restrict__ xr)
{
  __shared__ float xsT[NODE_DIM][16];
  int n0 = blockIdx.x * 16;
  int t = threadIdx.x;
  {
    int flat = t * 4;
    int i = flat >> 6, k = flat & 63;
    float4 v = *(const float4*)&x[(size_t)(n0 + i) * NODE_DIM + k];
    xsT[k + 0][i] = v.x; xsT[k + 1][i] = v.y; xsT[k + 2][i] = v.z; xsT[k + 3][i] = v.w;
  }
  __syncthreads();
  for (int m = 0; m < 2; m++) {
    const float* W  = m ? Wr : Wl;
    const float* bb = m ? br : bl;
    float* out = m ? xr : xl;
    for (int jh = 0; jh < 2; jh++) {
      int j = t + jh * 256;
      float acc[16];
      #pragma unroll
      for (int i = 0; i < 16; i++) acc[i] = 0.f;
      for (int k = 0; k < NODE_DIM; k++) {
        float w = W[k * HC1 + j];
        float xv[16];
        *(float4*)&xv[0]  = *(const float4*)&xsT[k][0];
        *(float4*)&xv[4]  = *(const float4*)&xsT[k][4];
        *(float4*)&xv[8]  = *(const float4*)&xsT[k][8];
        *(float4*)&xv[12] = *(const float4*)&xsT[k][12];
        #pragma unroll
        for (int i = 0; i < 16; i++) acc[i] = fmaf(xv[i], w, acc[i]);
      }
      float bj = bb[j];
      #pragma unroll
      for (int i = 0; i < 16; i++) out[(size_t)(n0 + i) * HC1 + j] = acc[i] + bj;
    }
  }
}

// ---------------- logits layer 1 (edge-parallel) ----------------
// block = 1024 = 16 waves = 4 groups(8 edges) x 4 heads; 32 edges per iter, 8 iters.
// lane owns channel pair c = h*128 + lane*2 (full head across the wave).
__global__ __launch_bounds__(1024, 2) void logits1_kernel(
    const float* __restrict__ ea, const int* __restrict__ srcs,
    const int* __restrict__ dsts, const float* __restrict__ We,
    const float* __restrict__ att, const float* __restrict__ xl,
    const float* __restrict__ xr, float* __restrict__ lg)
{
  __shared__ float Ws[EDGE_DIM * HC1];   // 64KB
  __shared__ float eas[32 * EDGE_DIM];   // 4KB
  __shared__ int sL[32], dL[32];
  int t = threadIdx.x;
  for (int i = t * 4; i < EDGE_DIM * HC1; i += 4096)
    *(float4*)&Ws[i] = *(const float4*)&We[i];
  int wave = t >> 6, lane = t & 63;
  int g = wave >> 2, h = wave & 3;
  int c = h * HID + lane * 2;
  float2 atv = *(const float2*)&att[c];
  for (int it = 0; it < 8; ++it) {
    int e0 = (blockIdx.x * 8 + it) * 32;
    __syncthreads();                     // protect eas/sL reuse (covers Ws on it==0)
    eas[t] = ea[(size_t)e0 * EDGE_DIM + t];
    if (t < 32) { sL[t] = srcs[e0 + t]; dL[t] = dsts[e0 + t]; }
    __syncthreads();
    const float* easg = &eas[g * 8 * EDGE_DIM];
    float acc[8][2];
    #pragma unroll
    for (int j = 0; j < 8; j++) { acc[j][0] = 0.f; acc[j][1] = 0.f; }
    #pragma unroll 1
    for (int kk = 0; kk < 8; kk++) {
      float2 w0 = *(const float2*)&Ws[(kk * 4 + 0) * HC1 + c];
      float2 w1 = *(const float2*)&Ws[(kk * 4 + 1) * HC1 + c];
      float2 w2 = *(const float2*)&Ws[(kk * 4 + 2) * HC1 + c];
      float2 w3 = *(const float2*)&Ws[(kk * 4 + 3) * HC1 + c];
      #pragma unroll
      for (int jh = 0; jh < 2; jh++) {
        float av[4][4];
        #pragma unroll
        for (int j = 0; j < 4; j++)
          *(float4*)&av[j][0] = *(const float4*)&easg[(jh * 4 + j) * EDGE_DIM + kk * 4];
        #pragma unroll
        for (int j = 0; j < 4; j++) {
          int jj = jh * 4 + j;
          acc[jj][0] = fmaf(av[j][0], w0.x, acc[jj][0]);
          acc[jj][1] = fmaf(av[j][0], w0.y, acc[jj][1]);
          acc[jj][0] = fmaf(av[j][1], w1.x, acc[jj][0]);
          acc[jj][1] = fmaf(av[j][1], w1.y, acc[jj][1]);
          acc[jj][0] = fmaf(av[j][2], w2.x, acc[jj][0]);
          acc[jj][1] = fmaf(av[j][2], w2.y, acc[jj][1]);
          acc[jj][0] = fmaf(av[j][3], w3.x, acc[jj][0]);
          acc[jj][1] = fmaf(av[j][3], w3.y, acc[jj][1]);
        }
      }
    }
    // tail: z = acc + xl[s] + xr[d]; lrelu; dot att; 64-lane butterfly
    #pragma unroll
    for (int jh = 0; jh < 2; jh++) {
      float2 xlv[4], xrv[4];
      #pragma unroll
      for (int j = 0; j < 4; j++) {
        int jj = jh * 4 + j;
        xlv[j] = *(const float2*)&xl[(size_t)sL[g * 8 + jj] * HC1 + c];
        xrv[j] = *(const float2*)&xr[(size_t)dL[g * 8 + jj] * HC1 + c];
      }
      #pragma unroll
      for (int j = 0; j < 4; j++) {
        int jj = jh * 4 + j;
        float z0 = acc[jj][0] + xlv[j].x + xrv[j].x;
        float z1 = acc[jj][1] + xlv[j].y + xrv[j].y;
        z0 = z0 > 0.f ? z0 : NEG_SLOPE * z0;
        z1 = z1 > 0.f ? z1 : NEG_SLOPE * z1;
        float s = z0 * atv.x + z1 * atv.y;
        #pragma unroll
        for (int o = 1; o < 64; o <<= 1) s += __shfl_xor(s, o);
        if (lane == 0) lg[(size_t)(e0 + g * 8 + jj) * HEADS + h] = s;
      }
    }
  }
}

// ---------------- agg layer 1 (per-node, no LDS) ----------------
template<bool H1BF>
__global__ __launch_bounds__(256, 8) void agg1_kernel(
    const int* __restrict__ offs, const int* __restrict__ csr,
    const int* __restrict__ srcs, const float* __restrict__ lg,
    const float* __restrict__ xl, const float* __restrict__ bias,
    void* __restrict__ h1out)
{
  int t = threadIdx.x, wave = t >> 6, lane = t & 63;
  int n = blockIdx.x * 4 + wave;
  int beg = offs[n], end = offs[n + 1];
  int deg = end - beg;
  int c0 = lane * 8, h = lane >> 4;
  float mx, my, mz, mw, sx, sy, sz, sw;
  if (deg <= 64) {
    float4 l4 = make_float4(-3.0e38f, -3.0e38f, -3.0e38f, -3.0e38f);
    if (lane < deg) l4 = *(const float4*)&lg[(size_t)csr[beg + lane] * HEADS];
    mx = l4.x; my = l4.y; mz = l4.z; mw = l4.w;
    #pragma unroll
    for (int o = 1; o < 64; o <<= 1) {
      mx = fmaxf(mx, __shfl_xor(mx, o));
      my = fmaxf(my, __shfl_xor(my, o));
      mz = fmaxf(mz, __shfl_xor(mz, o));
      mw = fmaxf(mw, __shfl_xor(mw, o));
    }
    sx = (lane < deg) ? __expf(l4.x - mx) : 0.f;
    sy = (lane < deg) ? __expf(l4.y - my) : 0.f;
    sz = (lane < deg) ? __expf(l4.z - mz) : 0.f;
    sw = (lane < deg) ? __expf(l4.w - mw) : 0.f;
    #pragma unroll
    for (int o = 1; o < 64; o <<= 1) {
      sx += __shfl_xor(sx, o); sy += __shfl_xor(sy, o);
      sz += __shfl_xor(sz, o); sw += __shfl_xor(sw, o);
    }
  } else {
    mx = my = mz = mw = -3.0e38f;
    for (int i0 = beg; i0 < end; i0 += 64) {
      if (i0 + lane < end) {
        float4 l4 = *(const float4*)&lg[(size_t)csr[i0 + lane] * HEADS];
        mx = fmaxf(mx, l4.x); my = fmaxf(my, l4.y);
        mz = fmaxf(mz, l4.z); mw = fmaxf(mw, l4.w);
      }
    }
    #pragma unroll
    for (int o = 1; o < 64; o <<= 1) {
      mx = fmaxf(mx, __shfl_xor(mx, o));
      my = fmaxf(my, __shfl_xor(my, o));
      mz = fmaxf(mz, __shfl_xor(mz, o));
      mw = fmaxf(mw, __shfl_xor(mw, o));
    }
    sx = sy = sz = sw = 0.f;
    for (int i0 = beg; i0 < end; i0 += 64) {
      if (i0 + lane < end) {
        float4 l4 = *(const float4*)&lg[(size_t)csr[i0 + lane] * HEADS];
        sx += __expf(l4.x - mx); sy += __expf(l4.y - my);
        sz += __expf(l4.z - mz); sw += __expf(l4.w - mw);
      }
    }
    #pragma unroll
    for (int o = 1; o < 64; o <<= 1) {
      sx += __shfl_xor(sx, o); sy += __shfl_xor(sy, o);
      sz += __shfl_xor(sz, o); sw += __shfl_xor(sw, o);
    }
  }
  float mh = (h == 0) ? mx : (h == 1) ? my : (h == 2) ? mz : mw;
  float dh = (h == 0) ? sx : (h == 1) ? sy : (h == 2) ? sz : sw;
  float invd = dh > 0.f ? 1.f / dh : 0.f;
  float acc[8] = {0.f,0.f,0.f,0.f,0.f,0.f,0.f,0.f};
  int ev = 0, sv = 0;
  if (lane < 8 && beg + lane < end) { ev = csr[beg + lane]; sv = srcs[ev]; }
  for (int i0 = beg; i0 < end; i0 += 8) {
    int nv = end - i0; if (nv > 8) nv = 8;
    int earr[8], sarr[8];
    #pragma unroll
    for (int j = 0; j < 8; j++) { earr[j] = __shfl(ev, j); sarr[j] = __shfl(sv, j); }
    if (lane < 8 && i0 + 8 + lane < end) { ev = csr[i0 + 8 + lane]; sv = srcs[ev]; }
    #pragma unroll
    for (int jh = 0; jh < 2; jh++) {
      float lgj[4]; float xv[4][8];
      #pragma unroll
      for (int j = 0; j < 4; j++) {
        int jj = jh * 4 + j;
        if (jj < nv) {
          lgj[j] = lg[(size_t)earr[jj] * HEADS + h];
          const float* p = &xl[(size_t)sarr[jj] * HC1 + c0];
          *(float4*)&xv[j][0] = *(const float4*)p;
          *(float4*)&xv[j][4] = *(const float4*)(p + 4);
        }
      }
      #pragma unroll
      for (int j = 0; j < 4; j++) {
        int jj = jh * 4 + j;
        if (jj < nv) {
          float pw = __expf(lgj[j] - mh) * invd;
          #pragma unroll
          for (int k = 0; k < 8; k++) acc[k] = fmaf(pw, xv[j][k], acc[k]);
        }
      }
    }
  }
  float r[8];
  #pragma unroll
  for (int k = 0; k < 8; k++) {
    float v = acc[k] + bias[c0 + k];
    r[k] = v > 0.f ? v : 0.f;            // relu after conv1
  }
  if (H1BF) {
    unsigned short* hb = (unsigned short*)h1out;
    ushort4 ua, ub;
    ua.x = f2b(r[0]); ua.y = f2b(r[1]); ua.z = f2b(r[2]); ua.w = f2b(r[3]);
    ub.x = f2b(r[4]); ub.y = f2b(r[5]); ub.z = f2b(r[6]); ub.w = f2b(r[7]);
    *(ushort4*)&hb[(size_t)n * HC1 + c0]     = ua;
    *(ushort4*)&hb[(size_t)n * HC1 + c0 + 4] = ub;
  } else {
    float* hf = (float*)h1out;
    *(float4*)&hf[(size_t)n * HC1 + c0]     = *(float4*)&r[0];
    *(float4*)&hf[(size_t)n * HC1 + c0 + 4] = *(float4*)&r[4];
  }
}

// ---------------- linear2 ----------------
template<bool INBF>
__global__ __launch_bounds__(256) void linear2_kernel(
    const void* __restrict__ hin_, const float* __restrict__ Wl,
    const float* __restrict__ bl, const float* __restrict__ Wr,
    const float* __restrict__ br, float* __restrict__ xl, float* __restrict__ xr)
{
  __shared__ float xsT[HC1][16];   // 32KB
  int n0 = blockIdx.x * 16;
  int t = threadIdx.x;
  for (int r = 0; r < 8; r++) {
    int flat = (t + r * 256) * 4;
    int i = flat >> 9, k = flat & 511;
    float4 v;
    if (INBF) {
      const unsigned short* hb = (const unsigned short*)hin_;
      ushort4 u = *(const ushort4*)&hb[(size_t)(n0 + i) * HC1 + k];
      v.x = b2f(u.x); v.y = b2f(u.y); v.z = b2f(u.z); v.w = b2f(u.w);
    } else {
      const float* hf = (const float*)hin_;
      v = *(const float4*)&hf[(size_t)(n0 + i) * HC1 + k];
    }
    xsT[k + 0][i] = v.x; xsT[k + 1][i] = v.y; xsT[k + 2][i] = v.z; xsT[k + 3][i] = v.w;
  }
  __syncthreads();
  int m = t >> 7, j = t & 127;
  const float* W = m ? Wr : Wl;
  float bj = (m ? br : bl)[j];
  float* out = m ? xr : xl;
  float acc[16];
  #pragma unroll
  for (int i = 0; i < 16; i++) acc[i] = 0.f;
  for (int k = 0; k < HC1; k++) {
    float w = W[k * HID + j];
    float xv[16];
    *(float4*)&xv[0]  = *(const float4*)&xsT[k][0];
    *(float4*)&xv[4]  = *(const float4*)&xsT[k][4];
    *(float4*)&xv[8]  = *(const float4*)&xsT[k][8];
    *(float4*)&xv[12] = *(const float4*)&xsT[k][12];
    #pragma unroll
    for (int i = 0; i < 16; i++) acc[i] = fmaf(xv[i], w, acc[i]);
  }
  #pragma unroll
  for (int i = 0; i < 16; i++) out[(size_t)(n0 + i) * HID + j] = acc[i] + bj;
}

// ---------------- logits layer 2 (edge-parallel) ----------------
// block = 1024 = 16 waves; wave = 8 edges x 128 ch (2 ch/lane); 128 edges/iter, 2 iters.
__global__ __launch_bounds__(1024, 2) void logits2_kernel(
    const float* __restrict__ ea, const int* __restrict__ srcs,
    const int* __restrict__ dsts, const float* __restrict__ We,
    const float* __restrict__ att, const float* __restrict__ xl,
    const float* __restrict__ xr, float* __restrict__ lg)
{
  __shared__ float Ws[EDGE_DIM * HID];    // 16KB
  __shared__ float eas[128 * EDGE_DIM];   // 16KB
  __shared__ int sL[128], dL[128];
  int t = threadIdx.x;
  for (int i = t * 4; i < EDGE_DIM * HID; i += 4096)
    *(float4*)&Ws[i] = *(const float4*)&We[i];
  int wave = t >> 6, lane = t & 63;
  int c = lane * 2;
  float2 atv = *(const float2*)&att[c];
  for (int it = 0; it < 2; ++it) {
    int e0 = (blockIdx.x * 2 + it) * 128;
    __syncthreads();
    *(float4*)&eas[t * 4] = *(const float4*)&ea[(size_t)e0 * EDGE_DIM + t * 4];
    if (t < 128) { sL[t] = srcs[e0 + t]; dL[t] = dsts[e0 + t]; }
    __syncthreads();
    const float* easg = &eas[wave * 8 * EDGE_DIM];
    float acc[8][2];
    #pragma unroll
    for (int j = 0; j < 8; j++) { acc[j][0] = 0.f; acc[j][1] = 0.f; }
    #pragma unroll 1
    for (int kk = 0; kk < 8; kk++) {
      float2 w0 = *(const float2*)&Ws[(kk * 4 + 0) * HID + c];
      float2 w1 = *(const float2*)&Ws[(kk * 4 + 1) * HID + c];
      float2 w2 = *(const float2*)&Ws[(kk * 4 + 2) * HID + c];
      float2 w3 = *(const float2*)&Ws[(kk * 4 + 3) * HID + c];
      #pragma unroll
      for (int jh = 0; jh < 2; jh++) {
        float av[4][4];
        #pragma unroll
        for (int j = 0; j < 4; j++)
          *(float4*)&av[j][0] = *(const float4*)&easg[(jh * 4 + j) * EDGE_DIM + kk * 4];
        #pragma unroll
        for (int j = 0; j < 4; j++) {
          int jj = jh * 4 + j;
          acc[jj][0] = fmaf(av[j][0], w0.x, acc[jj][0]);
          acc[jj][1] = fmaf(av[j][0], w0.y, acc[jj][1]);
          acc[jj][0] = fmaf(av[j][1], w1.x, acc[jj][0]);
          acc[jj][1] = fmaf(av[j][1], w1.y, acc[jj][1]);
          acc[jj][0] = fmaf(av[j][2], w2.x, acc[jj][0]);
          acc[jj][1] = fmaf(av[j][2], w2.y, acc[jj][1]);
          acc[jj][0] = fmaf(av[j][3], w3.x, acc[jj][0]);
          acc[jj][1] = fmaf(av[j][3], w3.y, acc[jj][1]);
        }
      }
    }
    #pragma unroll
    for (int jh = 0; jh < 2; jh++) {
      float2 xlv[4], xrv[4];
      #pragma unroll
      for (int j = 0; j < 4; j++) {
        int jj = jh * 4 + j;
        xlv[j] = *(const float2*)&xl[(size_t)sL[wave * 8 + jj] * HID + c];
        xrv[j] = *(const float2*)&xr[(size_t)dL[wave * 8 + jj] * HID + c];
      }
      #pragma unroll
      for (int j = 0; j < 4; j++) {
        int jj = jh * 4 + j;
        float z0 = acc[jj][0] + xlv[j].x + xrv[j].x;
        float z1 = acc[jj][1] + xlv[j].y + xrv[j].y;
        z0 = z0 > 0.f ? z0 : NEG_SLOPE * z0;
        z1 = z1 > 0.f ? z1 : NEG_SLOPE * z1;
        float s = z0 * atv.x + z1 * atv.y;
        #pragma unroll
        for (int o = 1; o < 64; o <<= 1) s += __shfl_xor(s, o);
        if (lane == 0) lg[e0 + wave * 8 + jj] = s;
      }
    }
  }
}

// ---------------- agg layer 2 (per-node, no LDS) ----------------
__global__ __launch_bounds__(256, 8) void agg2_kernel(
    const int* __restrict__ offs, const int* __restrict__ csr,
    const int* __restrict__ srcs, const float* __restrict__ lg,
    const float* __restrict__ xl, const float* __restrict__ bias,
    float* __restrict__ h2out)
{
  int t = threadIdx.x, wave = t >> 6, lane = t & 63;
  int n = blockIdx.x * 4 + wave;
  int beg = offs[n], end = offs[n + 1];
  int deg = end - beg;
  int c0 = lane * 2;
  float m, d;
  if (deg <= 64) {
    float l = -3.0e38f;
    if (lane < deg) l = lg[csr[beg + lane]];
    m = l;
    #pragma unroll
    for (int o = 1; o < 64; o <<= 1) m = fmaxf(m, __shfl_xor(m, o));
    d = (lane < deg) ? __expf(l - m) : 0.f;
    #pragma unroll
    for (int o = 1; o < 64; o <<= 1) d += __shfl_xor(d, o);
  } else {
    m = -3.0e38f;
    for (int i0 = beg; i0 < end; i0 += 64)
      if (i0 + lane < end) m = fmaxf(m, lg[csr[i0 + lane]]);
    #pragma unroll
    for (int o = 1; o < 64; o <<= 1) m = fmaxf(m, __shfl_xor(m, o));
    d = 0.f;
    for (int i0 = beg; i0 < end; i0 += 64)
      if (i0 + lane < end) d += __expf(lg[csr[i0 + lane]] - m);
    #pragma unroll
    for (int o = 1; o < 64; o <<= 1) d += __shfl_xor(d, o);
  }
  float invd = d > 0.f ? 1.f / d : 0.f;
  float a0 = 0.f, a1 = 0.f;
  int ev = 0, sv = 0;
  if (lane < 8 && beg + lane < end) { ev = csr[beg + lane]; sv = srcs[ev]; }
  for (int i0 = beg; i0 < end; i0 += 8) {
    int nv = end - i0; if (nv > 8) nv = 8;
    int earr[8], sarr[8];
    #pragma unroll
    for (int j = 0; j < 8; j++) { earr[j] = __shfl(ev, j); sarr[j] = __shfl(sv, j); }
    if (lane < 8 && i0 + 8 + lane < end) { ev = csr[i0 + 8 + lane]; sv = srcs[ev]; }
    float lgj[8]; float2 xv[8];
    #pragma unroll
    for (int j = 0; j < 8; j++) {
      if (j < nv) {
        lgj[j] = lg[earr[j]];
        xv[j] = *(const float2*)&xl[(size_t)sarr[j] * HID + c0];
      }
    }
    #pragma unroll
    for (int j = 0; j < 8; j++) {
      if (j < nv) {
        float pw = __expf(lgj[j] - m) * invd;
        a0 = fmaf(pw, xv[j].x, a0);
        a1 = fmaf(pw, xv[j].y, a1);
      }
    }
  }
  float2 o2 = make_float2(a0 + bias[c0], a1 + bias[c0 + 1]);  // no relu after conv2
  *(float2*)&h2out[(size_t)n * HID + c0] = o2;
}

// ---------------- MLP head ----------------
__global__ __launch_bounds__(256) void head_kernel(
    const float* __restrict__ h2, const float* __restrict__ Wh1,
    const float* __restrict__ bh1, const float* __restrict__ Wh2,
    const float* __restrict__ bh2, float* __restrict__ out)
{
  __shared__ float hs[16][HID];   // 8KB
  __shared__ float ts[16][64];    // 4KB
  int n0 = blockIdx.x * 16;
  int t = threadIdx.x;
  for (int r = 0; r < 2; r++) {
    int flat = (t + r * 256) * 4; // 2048 floats
    int i = flat >> 7, k = flat & 127;
    *(float4*)&hs[i][k] = *(const float4*)&h2[(size_t)(n0 + i) * HID + k];
  }
  __syncthreads();
  int j = t & 63, g = t >> 6;
  float acc[4];
  #pragma unroll
  for (int q = 0; q < 4; q++) acc[q] = 0.f;
  for (int k = 0; k < HID; k++) {
    float w = Wh1[k * 64 + j];
    #pragma unroll
    for (int q = 0; q < 4; q++) acc[q] = fmaf(hs[g + 4 * q][k], w, acc[q]);
  }
  float bj = bh1[j];
  #pragma unroll
  for (int q = 0; q < 4; q++) {
    float v = acc[q] + bj;
    ts[g + 4 * q][j] = v > 0.f ? v : 0.f;
  }
  __syncthreads();
  if (t < 32) {
    int nl = t >> 1, k = t & 1;
    float acc2 = bh2[k];
    for (int jj = 0; jj < 64; jj++) acc2 = fmaf(ts[nl][jj], Wh2[jj * 2 + k], acc2);
    out[(size_t)(n0 + nl) * 2 + k] = acc2;
  }
}

extern "C" void kernel_launch(void* const* d_in, const int* in_sizes, int n_in,
                              void* d_out, int out_size, void* d_ws, size_t ws_size,
                              hipStream_t stream)
{
  (void)in_sizes; (void)n_in; (void)out_size;
  const float* x    = (const float*)d_in[0];
  const int* eidx   = (const int*)d_in[1];
  const float* ea   = (const float*)d_in[2];
  const float* Wl1  = (const float*)d_in[3];
  const float* bl1  = (const float*)d_in[4];
  const float* Wr1  = (const float*)d_in[5];
  const float* br1  = (const float*)d_in[6];
  const float* We1  = (const float*)d_in[7];
  const float* att1 = (const float*)d_in[8];
  const float* bias1= (const float*)d_in[9];
  const float* Wl2  = (const float*)d_in[10];
  const float* bl2  = (const float*)d_in[11];
  const float* Wr2  = (const float*)d_in[12];
  const float* br2  = (const float*)d_in[13];
  const float* We2  = (const float*)d_in[14];
  const float* att2 = (const float*)d_in[15];
  const float* bias2= (const float*)d_in[16];
  const float* Wh1  = (const float*)d_in[17];
  const float* bh1  = (const float*)d_in[18];
  const float* Wh2  = (const float*)d_in[19];
  const float* bh2  = (const float*)d_in[20];
  const int* srcs = eidx;
  const int* dsts = eidx + N_EDGES;
  float* out = (float*)d_out;

  const size_t szBig = (size_t)N_NODES * HC1 * sizeof(float);
  auto aln = [](size_t b) { return (b + 511) & ~(size_t)511; };
  size_t smallSz = aln((size_t)N_NODES * 4) * 2 + aln((size_t)(N_NODES + 1) * 4)
                 + aln((size_t)N_EDGES * 4) + aln((size_t)N_EDGES * HEADS * 4);
  size_t needF = aln(szBig) * 3 + smallSz + 4096;
  bool useBF = ws_size < needF;

  char* p = (char*)d_ws;
  auto alloc = [&](size_t bytes) { char* q = p; p += (bytes + 511) & ~(size_t)511; return q; };
  float* xl1 = (float*)alloc(szBig);
  float* xr1 = (float*)alloc(szBig);          // reused for xl2/xr2 after logits1
  void*  h1  = (void*)alloc(useBF ? szBig / 2 : szBig);
  float* lgbuf = (float*)alloc((size_t)N_EDGES * HEADS * 4);  // logits L1; reused scalar L2
  int* deg    = (int*)alloc((size_t)N_NODES * 4);
  int* offs   = (int*)alloc((size_t)(N_NODES + 1) * 4);
  int* cursor = (int*)alloc((size_t)N_NODES * 4);
  int* csr    = (int*)alloc((size_t)N_EDGES * 4);
  float* xl2 = xr1;
  float* xr2 = xr1 + (size_t)N_NODES * HID;
  float* h2  = xl1;                            // xl1 region dead after agg1

  hipLaunchKernelGGL(zero_deg_kernel, dim3((N_NODES + 255) / 256), dim3(256), 0, stream, deg);
  hipLaunchKernelGGL(deg_count_kernel, dim3((N_EDGES + 255) / 256), dim3(256), 0, stream, dsts, deg);
  hipLaunchKernelGGL(scan_kernel, dim3(1), dim3(1024), 0, stream, deg, offs, cursor);
  hipLaunchKernelGGL(scatter_kernel, dim3((N_EDGES + 255) / 256), dim3(256), 0, stream, dsts, cursor, csr);
  hipLaunchKernelGGL(linear1_kernel, dim3(N_NODES / 16), dim3(256), 0, stream,
                     x, Wl1, bl1, Wr1, br1, xl1, xr1);
  hipLaunchKernelGGL(logits1_kernel, dim3(N_EDGES / 256), dim3(1024), 0, stream,
                     ea, srcs, dsts, We1, att1, xl1, xr1, lgbuf);
  if (useBF)
    hipLaunchKernelGGL((agg1_kernel<true>), dim3(N_NODES / 4), dim3(256), 0, stream,
                       offs, csr, srcs, lgbuf, xl1, bias1, h1);
  else
    hipLaunchKernelGGL((agg1_kernel<false>), dim3(N_NODES / 4), dim3(256), 0, stream,
                       offs, csr, srcs, lgbuf, xl1, bias1, h1);
  if (useBF)
    hipLaunchKernelGGL((linear2_kernel<true>), dim3(N_NODES / 16), dim3(256), 0, stream,
                       h1, Wl2, bl2, Wr2, br2, xl2, xr2);
  else
    hipLaunchKernelGGL((linear2_kernel<false>), dim3(N_NODES / 16), dim3(256), 0, stream,
                       h1, Wl2, bl2, Wr2, br2, xl2, xr2);
  hipLaunchKernelGGL(logits2_kernel, dim3(N_EDGES / 256), dim3(1024), 0, stream,
                     ea, srcs, dsts, We2, att2, xl2, xr2, lgbuf);
  hipLaunchKernelGGL(agg2_kernel, dim3(N_NODES / 4), dim3(256), 0, stream,
                     offs, csr, srcs, lgbuf, xl2, bias2, h2);
  hipLaunchKernelGGL(head_kernel, dim3(N_NODES / 16), dim3(256), 0, stream,
                     h2, Wh1, bh1, Wh2, bh2, out);
}

// Round 9
// 667.051 us; speedup vs baseline: 1.4078x; 1.4078x over previous
//
#include <hip/hip_runtime.h>
#include <hip/hip_bf16.h>
#include <math.h>

#define N_NODES 20000
#define N_EDGES 320000
#define NODE_DIM 64
#define EDGE_DIM 32
#define HID 128
#define HEADS 4
#define HC1 512   // HEADS*HID
#define NEG_SLOPE 0.2f

__device__ __forceinline__ unsigned short f2b(float f) {
  unsigned u = __float_as_uint(f);
  unsigned r = (u + 0x7fffu + ((u >> 16) & 1u)) >> 16;
  return (unsigned short)r;
}
__device__ __forceinline__ float b2f(unsigned short b) {
  return __uint_as_float(((unsigned)b) << 16);
}

// ---------------- CSR build + degree sort ----------------
__global__ void zero_deg_kernel(int* deg, int* hist) {
  int i = blockIdx.x * blockDim.x + threadIdx.x;
  if (i < N_NODES) deg[i] = 0;
  if (i < 64) hist[i] = 0;
}

__global__ void deg_count_kernel(const int* __restrict__ dsts, int* __restrict__ deg) {
  int e = blockIdx.x * blockDim.x + threadIdx.x;
  if (e < N_EDGES) atomicAdd(&deg[dsts[e]], 1);
}

__global__ void hist_kernel(const int* __restrict__ deg, int* __restrict__ hist) {
  int n = blockIdx.x * blockDim.x + threadIdx.x;
  if (n >= N_NODES) return;
  int k = deg[n]; k = k > 63 ? 63 : k;
  atomicAdd(&hist[63 - k], 1);           // descending degree order (LPT)
}

__global__ void histscan_kernel(const int* __restrict__ hist, int* __restrict__ cursor2) {
  int lane = threadIdx.x;                 // 64 threads
  int v = hist[lane];
  int s = v;
  #pragma unroll
  for (int o = 1; o < 64; o <<= 1) { int u = __shfl_up(s, o); if (lane >= o) s += u; }
  cursor2[lane] = s - v;                  // exclusive prefix
}

__global__ void permscatter_kernel(const int* __restrict__ deg, int* __restrict__ cursor2,
                                   int* __restrict__ perm) {
  int n = blockIdx.x * blockDim.x + threadIdx.x;
  if (n >= N_NODES) return;
  int k = deg[n]; k = k > 63 ? 63 : k;
  int pos = atomicAdd(&cursor2[63 - k], 1);
  perm[pos] = n;
}

__global__ __launch_bounds__(1024) void scan_kernel(
    const int* __restrict__ deg, int* __restrict__ offs, int* __restrict__ cursor)
{
  __shared__ int part[1024];
  int t = threadIdx.x;
  const int C = 20;                 // 1024*20 = 20480 >= N_NODES
  int base = t * C;
  int loc[C]; int s = 0;
  #pragma unroll
  for (int i = 0; i < C; i++) { loc[i] = s; int idx = base + i; s += (idx < N_NODES) ? deg[idx] : 0; }
  part[t] = s;
  __syncthreads();
  for (int off = 1; off < 1024; off <<= 1) {
    int v = (t >= off) ? part[t - off] : 0;
    __syncthreads();
    part[t] += v;
    __syncthreads();
  }
  int pbase = (t > 0) ? part[t - 1] : 0;
  #pragma unroll
  for (int i = 0; i < C; i++) {
    int idx = base + i;
    if (idx < N_NODES) { int o = pbase + loc[i]; offs[idx] = o; cursor[idx] = o; }
  }
  if (t == 1023) offs[N_NODES] = part[1023];
}

__global__ void scatter_kernel(const int* __restrict__ dsts, int* __restrict__ cursor,
                               int* __restrict__ csr) {
  int e = blockIdx.x * blockDim.x + threadIdx.x;
  if (e >= N_EDGES) return;
  int pos = atomicAdd(&cursor[dsts[e]], 1);
  csr[pos] = e;
}

// ---------------- linear1 ----------------
__global__ __launch_bounds__(256) void linear1_kernel(
    const float* __restrict__ x, const float* __restrict__ Wl,
    const float* __restrict__ bl, const float* __restrict__ Wr,
    const float* __restrict__ br, float* __restrict__ xl, float* __restrict__ xr)
{
  __shared__ float xsT[NODE_DIM][16];
  int n0 = blockIdx.x * 16;
  int t = threadIdx.x;
  {
    int flat = t * 4;
    int i = flat >> 6, k = flat & 63;
    float4 v = *(const float4*)&x[(size_t)(n0 + i) * NODE_DIM + k];
    xsT[k + 0][i] = v.x; xsT[k + 1][i] = v.y; xsT[k + 2][i] = v.z; xsT[k + 3][i] = v.w;
  }
  __syncthreads();
  for (int m = 0; m < 2; m++) {
    const float* W  = m ? Wr : Wl;
    const float* bb = m ? br : bl;
    float* out = m ? xr : xl;
    for (int jh = 0; jh < 2; jh++) {
      int j = t + jh * 256;
      float acc[16];
      #pragma unroll
      for (int i = 0; i < 16; i++) acc[i] = 0.f;
      for (int k = 0; k < NODE_DIM; k++) {
        float w = W[k * HC1 + j];
        float xv[16];
        *(float4*)&xv[0]  = *(const float4*)&xsT[k][0];
        *(float4*)&xv[4]  = *(const float4*)&xsT[k][4];
        *(float4*)&xv[8]  = *(const float4*)&xsT[k][8];
        *(float4*)&xv[12] = *(const float4*)&xsT[k][12];
        #pragma unroll
        for (int i = 0; i < 16; i++) acc[i] = fmaf(xv[i], w, acc[i]);
      }
      float bj = bb[j];
      #pragma unroll
      for (int i = 0; i < 16; i++) out[(size_t)(n0 + i) * HC1 + j] = acc[i] + bj;
    }
  }
}

// ---------------- fused layer 1 (half-split: 32KB Ws) ----------------
// block = 1024 threads = 16 waves = 16 nodes x ONE half (half = blockIdx&1).
// lane owns 4 channels: C = half*256 + lane*4; head = C>>7, 32-lane butterfly groups.
// LDS = 32KB (Ws half) + 8KB (eas) -> 2 blocks/CU resident under any LDS limit.
template<bool H1BF>
__global__ __launch_bounds__(1024, 2) void fused1_kernel(
    const float* __restrict__ ea, const int* __restrict__ srcs,
    const float* __restrict__ We, const float* __restrict__ att,
    const float* __restrict__ xl, const float* __restrict__ xr,
    const float* __restrict__ bias, const int* __restrict__ offs,
    const int* __restrict__ csr, const int* __restrict__ perm,
    void* __restrict__ h1out)
{
  __shared__ float Ws[EDGE_DIM * 256];     // 32KB: this block's 256-col half of We
  __shared__ float eas[16][4][EDGE_DIM];   // 8KB, per-wave chunk ea tile
  int t = threadIdx.x;
  int half = blockIdx.x & 1;
  for (int i = t * 4; i < EDGE_DIM * 256; i += 4096) {
    int row = i >> 8, col = i & 255;
    *(float4*)&Ws[i] = *(const float4*)&We[(size_t)row * HC1 + half * 256 + col];
  }
  __syncthreads();
  int wave = t >> 6, lane = t & 63;
  int n = perm[(blockIdx.x >> 1) * 16 + wave];   // 1250 groups * 16 = 20000 exact
  int Cl = lane * 4;                 // channel within the half
  int C = half * 256 + Cl;           // global channel
  float at4[4], xr4[4];
  *(float4*)at4 = *(const float4*)&att[C];
  *(float4*)xr4 = *(const float4*)&xr[(size_t)n * HC1 + C];
  float o4[4] = {0.f,0.f,0.f,0.f};
  float mx = 8.0f, dn = 0.f;        // shift-invariant base; defer-max rescale below
  int beg = offs[n], end = offs[n + 1];
  int ev = 0, sv = 0;
  if (lane < 4 && beg + lane < end) { ev = csr[beg + lane]; sv = srcs[ev]; }
  for (int i0 = beg; i0 < end; i0 += 4) {
    int nv = end - i0; if (nv > 4) nv = 4;
    int sarr[4];
    #pragma unroll
    for (int j = 0; j < 4; j++) sarr[j] = __shfl(sv, j);
    // stage this chunk's ea rows into per-wave LDS (coalesced float2/lane)
    {
      int mye = __shfl(ev, lane >> 4);
      float2 eav = *(const float2*)&ea[(size_t)mye * EDGE_DIM + (lane & 15) * 2];
      *(float2*)&eas[wave][lane >> 4][(lane & 15) * 2] = eav;
    }
    // acc init = xl + xr (gather xl; frees the separate xl hold)
    float a4[4][4];
    #pragma unroll
    for (int j = 0; j < 4; j++) {
      if (j < nv) {
        float4 xv = *(const float4*)&xl[(size_t)sarr[j] * HC1 + C];
        a4[j][0] = xv.x + xr4[0]; a4[j][1] = xv.y + xr4[1];
        a4[j][2] = xv.z + xr4[2]; a4[j][3] = xv.w + xr4[3];
      } else {
        a4[j][0] = 0.f; a4[j][1] = 0.f; a4[j][2] = 0.f; a4[j][3] = 0.f;
      }
    }
    // prefetch next chunk's indices
    if (lane < 4 && i0 + 4 + lane < end) { ev = csr[i0 + 4 + lane]; sv = srcs[ev]; }
    // ee-GEMM: z = xl + xr + ea@We accumulated in place (Ws stride 256)
    #pragma unroll 1
    for (int kk = 0; kk < 8; kk++) {
      float w0[4], w1[4], w2[4], w3[4];
      *(float4*)w0 = *(const float4*)&Ws[(kk * 4 + 0) * 256 + Cl];
      *(float4*)w1 = *(const float4*)&Ws[(kk * 4 + 1) * 256 + Cl];
      *(float4*)w2 = *(const float4*)&Ws[(kk * 4 + 2) * 256 + Cl];
      *(float4*)w3 = *(const float4*)&Ws[(kk * 4 + 3) * 256 + Cl];
      #pragma unroll
      for (int j = 0; j < 4; j++) {
        float av[4];
        *(float4*)av = *(const float4*)&eas[wave][j][kk * 4];
        #pragma unroll
        for (int c = 0; c < 4; c++) {
          a4[j][c] = fmaf(av[0], w0[c], a4[j][c]);
          a4[j][c] = fmaf(av[1], w1[c], a4[j][c]);
          a4[j][c] = fmaf(av[2], w2[c], a4[j][c]);
          a4[j][c] = fmaf(av[3], w3[c], a4[j][c]);
        }
      }
    }
    // logits: leakyrelu + att dot, 32-lane (one head) butterflies
    float pl[4];
    #pragma unroll
    for (int j = 0; j < 4; j++) {
      float s = 0.f;
      #pragma unroll
      for (int c = 0; c < 4; c++) {
        float z = a4[j][c];
        float zm = z > 0.f ? z : NEG_SLOPE * z;
        s = fmaf(zm, at4[c], s);
      }
      #pragma unroll
      for (int o = 1; o <= 16; o <<= 1) s += __shfl_xor(s, o);
      pl[j] = (j < nv) ? s : -3.0e38f;
    }
    // issue xl re-gather now (latency covered by softmax math below)
    float xv0[4], xv1[4], xv2[4], xv3[4];
    if (0 < nv) *(float4*)xv0 = *(const float4*)&xl[(size_t)sarr[0] * HC1 + C];
    if (1 < nv) *(float4*)xv1 = *(const float4*)&xl[(size_t)sarr[1] * HC1 + C];
    if (2 < nv) *(float4*)xv2 = *(const float4*)&xl[(size_t)sarr[2] * HC1 + C];
    if (3 < nv) *(float4*)xv3 = *(const float4*)&xl[(size_t)sarr[3] * HC1 + C];
    // defer-max online softmax
    float cm = fmaxf(fmaxf(pl[0], pl[1]), fmaxf(pl[2], pl[3]));
    float mn = fmaxf(mx, cm);
    if (__any(mn > mx + 8.f)) {
      float fs = __expf(mx - mn);
      dn *= fs;
      #pragma unroll
      for (int c = 0; c < 4; c++) o4[c] *= fs;
      mx = mn;
    }
    float p[4];
    #pragma unroll
    for (int j = 0; j < 4; j++) p[j] = __expf(pl[j] - mx);
    dn += (p[0] + p[1]) + (p[2] + p[3]);
    if (0 < nv) { o4[0] = fmaf(p[0], xv0[0], o4[0]); o4[1] = fmaf(p[0], xv0[1], o4[1]);
                  o4[2] = fmaf(p[0], xv0[2], o4[2]); o4[3] = fmaf(p[0], xv0[3], o4[3]); }
    if (1 < nv) { o4[0] = fmaf(p[1], xv1[0], o4[0]); o4[1] = fmaf(p[1], xv1[1], o4[1]);
                  o4[2] = fmaf(p[1], xv1[2], o4[2]); o4[3] = fmaf(p[1], xv1[3], o4[3]); }
    if (2 < nv) { o4[0] = fmaf(p[2], xv2[0], o4[0]); o4[1] = fmaf(p[2], xv2[1], o4[1]);
                  o4[2] = fmaf(p[2], xv2[2], o4[2]); o4[3] = fmaf(p[2], xv2[3], o4[3]); }
    if (3 < nv) { o4[0] = fmaf(p[3], xv3[0], o4[0]); o4[1] = fmaf(p[3], xv3[1], o4[1]);
                  o4[2] = fmaf(p[3], xv3[2], o4[2]); o4[3] = fmaf(p[3], xv3[3], o4[3]); }
  }
  float iv = dn > 0.f ? 1.f / dn : 0.f;
  float r[4];
  #pragma unroll
  for (int c = 0; c < 4; c++) {
    float v = o4[c] * iv + bias[C + c];
    r[c] = v > 0.f ? v : 0.f;            // relu after conv1
  }
  if (H1BF) {
    unsigned short* hb = (unsigned short*)h1out;
    ushort4 u;
    u.x = f2b(r[0]); u.y = f2b(r[1]); u.z = f2b(r[2]); u.w = f2b(r[3]);
    *(ushort4*)&hb[(size_t)n * HC1 + C] = u;
  } else {
    float* hf = (float*)h1out;
    *(float4*)&hf[(size_t)n * HC1 + C] = *(float4*)r;
  }
}

// ---------------- linear2 ----------------
template<bool INBF>
__global__ __launch_bounds__(256) void linear2_kernel(
    const void* __restrict__ hin_, const float* __restrict__ Wl,
    const float* __restrict__ bl, const float* __restrict__ Wr,
    const float* __restrict__ br, float* __restrict__ xl, float* __restrict__ xr)
{
  __shared__ float xsT[HC1][16];   // 32KB
  int n0 = blockIdx.x * 16;
  int t = threadIdx.x;
  for (int r = 0; r < 8; r++) {
    int flat = (t + r * 256) * 4;
    int i = flat >> 9, k = flat & 511;
    float4 v;
    if (INBF) {
      const unsigned short* hb = (const unsigned short*)hin_;
      ushort4 u = *(const ushort4*)&hb[(size_t)(n0 + i) * HC1 + k];
      v.x = b2f(u.x); v.y = b2f(u.y); v.z = b2f(u.z); v.w = b2f(u.w);
    } else {
      const float* hf = (const float*)hin_;
      v = *(const float4*)&hf[(size_t)(n0 + i) * HC1 + k];
    }
    xsT[k + 0][i] = v.x; xsT[k + 1][i] = v.y; xsT[k + 2][i] = v.z; xsT[k + 3][i] = v.w;
  }
  __syncthreads();
  int m = t >> 7, j = t & 127;
  const float* W = m ? Wr : Wl;
  float bj = (m ? br : bl)[j];
  float* out = m ? xr : xl;
  float acc[16];
  #pragma unroll
  for (int i = 0; i < 16; i++) acc[i] = 0.f;
  for (int k = 0; k < HC1; k++) {
    float w = W[k * HID + j];
    float xv[16];
    *(float4*)&xv[0]  = *(const float4*)&xsT[k][0];
    *(float4*)&xv[4]  = *(const float4*)&xsT[k][4];
    *(float4*)&xv[8]  = *(const float4*)&xsT[k][8];
    *(float4*)&xv[12] = *(const float4*)&xsT[k][12];
    #pragma unroll
    for (int i = 0; i < 16; i++) acc[i] = fmaf(xv[i], w, acc[i]);
  }
  #pragma unroll
  for (int i = 0; i < 16; i++) out[(size_t)(n0 + i) * HID + j] = acc[i] + bj;
}

// ---------------- fused layer 2 (no head; eas-staged; chunk=8) ----------------
// block = 512 threads = 8 waves = 8 nodes. lane owns channels {lane, 64+lane}.
__global__ __launch_bounds__(512, 3) void fused2_kernel(
    const float* __restrict__ ea, const int* __restrict__ srcs,
    const float* __restrict__ We, const float* __restrict__ att,
    const float* __restrict__ xl, const float* __restrict__ xr,
    const float* __restrict__ bias, const int* __restrict__ offs,
    const int* __restrict__ csr, float* __restrict__ h2out)
{
  __shared__ float Ws[EDGE_DIM * HID];      // 16KB
  __shared__ float eas[8][8][EDGE_DIM];     // 8KB, per-wave chunk ea tile
  int t = threadIdx.x;
  for (int i = t * 4; i < EDGE_DIM * HID; i += 2048)
    *(float4*)&Ws[i] = *(const float4*)&We[i];
  __syncthreads();
  int wave = t >> 6, lane = t & 63;
  int n = blockIdx.x * 8 + wave;
  float ata = att[lane], atb = att[64 + lane];
  float xra = xr[(size_t)n * HID + lane], xrb = xr[(size_t)n * HID + 64 + lane];
  float oa = 0.f, ob = 0.f;
  float m = 8.0f, d = 0.f;
  int beg = offs[n], end = offs[n + 1];
  int ev = 0, sv = 0;
  if (lane < 8 && beg + lane < end) { ev = csr[beg + lane]; sv = srcs[ev]; }
  for (int i0 = beg; i0 < end; i0 += 8) {
    int nv = end - i0; if (nv > 8) nv = 8;
    int sarr[8];
    #pragma unroll
    for (int j = 0; j < 8; j++) sarr[j] = __shfl(sv, j);
    // stage this chunk's 8 ea rows into per-wave LDS (coalesced float4/lane)
    {
      int mye = __shfl(ev, lane >> 3);
      float4 eav = *(const float4*)&ea[(size_t)mye * EDGE_DIM + (lane & 7) * 4];
      *(float4*)&eas[wave][lane >> 3][(lane & 7) * 4] = eav;
    }
    // xl gathers issued before GEMM (latency hidden under FMA stream)
    float xa[8], xb[8];
    #pragma unroll
    for (int j = 0; j < 8; j++) {
      if (j < nv) {
        const float* p = &xl[(size_t)sarr[j] * HID];
        xa[j] = p[lane]; xb[j] = p[64 + lane];
      } else { xa[j] = 0.f; xb[j] = 0.f; }
    }
    // prefetch next chunk's indices
    if (lane < 8 && i0 + 8 + lane < end) { ev = csr[i0 + 8 + lane]; sv = srcs[ev]; }
    // ee-GEMM: LDS broadcast reads only
    float aa[8], ab[8];
    #pragma unroll
    for (int j = 0; j < 8; j++) { aa[j] = 0.f; ab[j] = 0.f; }
    #pragma unroll 2
    for (int kk = 0; kk < 8; kk++) {
      float av[8][4];
      #pragma unroll
      for (int j = 0; j < 8; j++)
        *(float4*)&av[j][0] = *(const float4*)&eas[wave][j][kk * 4];
      #pragma unroll
      for (int dk = 0; dk < 4; dk++) {
        float wA = Ws[(kk * 4 + dk) * HID + lane];
        float wB = Ws[(kk * 4 + dk) * HID + 64 + lane];
        #pragma unroll
        for (int j = 0; j < 8; j++) {
          aa[j] = fmaf(av[j][dk], wA, aa[j]);
          ab[j] = fmaf(av[j][dk], wB, ab[j]);
        }
      }
    }
    // logits: 8 independent 64-lane butterflies
    float pl[8];
    #pragma unroll
    for (int j = 0; j < 8; j++) {
      float za = aa[j] + xa[j] + xra;
      float zb = ab[j] + xb[j] + xrb;
      za = za > 0.f ? za : NEG_SLOPE * za;
      zb = zb > 0.f ? zb : NEG_SLOPE * zb;
      float s = za * ata + zb * atb;
      #pragma unroll
      for (int o = 1; o < 64; o <<= 1) s += __shfl_xor(s, o);
      pl[j] = (j < nv) ? s : -3.0e38f;
    }
    float cm = fmaxf(fmaxf(fmaxf(pl[0], pl[1]), fmaxf(pl[2], pl[3])),
                     fmaxf(fmaxf(pl[4], pl[5]), fmaxf(pl[6], pl[7])));
    float mn = fmaxf(m, cm);
    if (__any(mn > m + 8.f)) {
      float fs = __expf(m - mn);
      d *= fs; oa *= fs; ob *= fs;
      m = mn;
    }
    float p[8];
    #pragma unroll
    for (int j = 0; j < 8; j++) p[j] = __expf(pl[j] - m);
    d += ((p[0] + p[1]) + (p[2] + p[3])) + ((p[4] + p[5]) + (p[6] + p[7]));
    #pragma unroll
    for (int j = 0; j < 8; j++) {
      oa = fmaf(p[j], xa[j], oa);
      ob = fmaf(p[j], xb[j], ob);
    }
  }
  float invd = d > 0.f ? 1.f / d : 0.f;
  h2out[(size_t)n * HID + lane]      = oa * invd + bias[lane];
  h2out[(size_t)n * HID + 64 + lane] = ob * invd + bias[64 + lane];  // no relu after conv2
}

// ---------------- MLP head ----------------
__global__ __launch_bounds__(256) void head_kernel(
    const float* __restrict__ h2, const float* __restrict__ Wh1,
    const float* __restrict__ bh1, const float* __restrict__ Wh2,
    const float* __restrict__ bh2, float* __restrict__ out)
{
  __shared__ float hs[16][HID];   // 8KB
  __shared__ float ts[16][64];    // 4KB
  int n0 = blockIdx.x * 16;
  int t = threadIdx.x;
  for (int r = 0; r < 2; r++) {
    int flat = (t + r * 256) * 4; // 2048 floats
    int i = flat >> 7, k = flat & 127;
    *(float4*)&hs[i][k] = *(const float4*)&h2[(size_t)(n0 + i) * HID + k];
  }
  __syncthreads();
  int j = t & 63, g = t >> 6;
  float acc[4];
  #pragma unroll
  for (int q = 0; q < 4; q++) acc[q] = 0.f;
  for (int k = 0; k < HID; k++) {
    float w = Wh1[k * 64 + j];
    #pragma unroll
    for (int q = 0; q < 4; q++) acc[q] = fmaf(hs[g + 4 * q][k], w, acc[q]);
  }
  float bj = bh1[j];
  #pragma unroll
  for (int q = 0; q < 4; q++) {
    float v = acc[q] + bj;
    ts[g + 4 * q][j] = v > 0.f ? v : 0.f;
  }
  __syncthreads();
  if (t < 32) {
    int nl = t >> 1, k = t & 1;
    float acc2 = bh2[k];
    for (int jj = 0; jj < 64; jj++) acc2 = fmaf(ts[nl][jj], Wh2[jj * 2 + k], acc2);
    out[(size_t)(n0 + nl) * 2 + k] = acc2;
  }
}

extern "C" void kernel_launch(void* const* d_in, const int* in_sizes, int n_in,
                              void* d_out, int out_size, void* d_ws, size_t ws_size,
                              hipStream_t stream)
{
  (void)in_sizes; (void)n_in; (void)out_size;
  const float* x    = (const float*)d_in[0];
  const int* eidx   = (const int*)d_in[1];
  const float* ea   = (const float*)d_in[2];
  const float* Wl1  = (const float*)d_in[3];
  const float* bl1  = (const float*)d_in[4];
  const float* Wr1  = (const float*)d_in[5];
  const float* br1  = (const float*)d_in[6];
  const float* We1  = (const float*)d_in[7];
  const float* att1 = (const float*)d_in[8];
  const float* bias1= (const float*)d_in[9];
  const float* Wl2  = (const float*)d_in[10];
  const float* bl2  = (const float*)d_in[11];
  const float* Wr2  = (const float*)d_in[12];
  const float* br2  = (const float*)d_in[13];
  const float* We2  = (const float*)d_in[14];
  const float* att2 = (const float*)d_in[15];
  const float* bias2= (const float*)d_in[16];
  const float* Wh1  = (const float*)d_in[17];
  const float* bh1  = (const float*)d_in[18];
  const float* Wh2  = (const float*)d_in[19];
  const float* bh2  = (const float*)d_in[20];
  const int* srcs = eidx;
  const int* dsts = eidx + N_EDGES;
  float* out = (float*)d_out;

  const size_t szBig = (size_t)N_NODES * HC1 * sizeof(float);
  auto aln = [](size_t b) { return (b + 511) & ~(size_t)511; };
  size_t smallSz = aln((size_t)N_NODES * 4) * 3 + aln((size_t)(N_NODES + 1) * 4)
                 + aln((size_t)N_EDGES * 4) + aln(64 * 4) * 2;
  size_t needF = aln(szBig) * 3 + smallSz + 4096;
  bool useBF = ws_size < needF;

  char* p = (char*)d_ws;
  auto alloc = [&](size_t bytes) { char* q = p; p += (bytes + 511) & ~(size_t)511; return q; };
  float* xl1 = (float*)alloc(szBig);
  float* xr1 = (float*)alloc(szBig);          // reused for xl2/xr2 after fused1
  void*  h1  = (void*)alloc(useBF ? szBig / 2 : szBig);
  int* deg    = (int*)alloc((size_t)N_NODES * 4);
  int* offs   = (int*)alloc((size_t)(N_NODES + 1) * 4);
  int* cursor = (int*)alloc((size_t)N_NODES * 4);
  int* csr    = (int*)alloc((size_t)N_EDGES * 4);
  int* hist   = (int*)alloc(64 * 4);
  int* cursor2= (int*)alloc(64 * 4);
  int* perm   = (int*)alloc((size_t)N_NODES * 4);
  float* xl2 = xr1;
  float* xr2 = xr1 + (size_t)N_NODES * HID;
  float* h2  = xl1;                            // xl1 region dead after fused1

  hipLaunchKernelGGL(zero_deg_kernel, dim3((N_NODES + 255) / 256), dim3(256), 0, stream, deg, hist);
  hipLaunchKernelGGL(deg_count_kernel, dim3((N_EDGES + 255) / 256), dim3(256), 0, stream, dsts, deg);
  hipLaunchKernelGGL(hist_kernel, dim3((N_NODES + 255) / 256), dim3(256), 0, stream, deg, hist);
  hipLaunchKernelGGL(histscan_kernel, dim3(1), dim3(64), 0, stream, hist, cursor2);
  hipLaunchKernelGGL(permscatter_kernel, dim3((N_NODES + 255) / 256), dim3(256), 0, stream,
                     deg, cursor2, perm);
  hipLaunchKernelGGL(scan_kernel, dim3(1), dim3(1024), 0, stream, deg, offs, cursor);
  hipLaunchKernelGGL(scatter_kernel, dim3((N_EDGES + 255) / 256), dim3(256), 0, stream, dsts, cursor, csr);
  hipLaunchKernelGGL(linear1_kernel, dim3(N_NODES / 16), dim3(256), 0, stream,
                     x, Wl1, bl1, Wr1, br1, xl1, xr1);
  // fused1: grid = (N/16 node-groups) x 2 halves
  if (useBF)
    hipLaunchKernelGGL((fused1_kernel<true>), dim3((N_NODES / 16) * 2), dim3(1024), 0, stream,
                       ea, srcs, We1, att1, xl1, xr1, bias1, offs, csr, perm, h1);
  else
    hipLaunchKernelGGL((fused1_kernel<false>), dim3((N_NODES / 16) * 2), dim3(1024), 0, stream,
                       ea, srcs, We1, att1, xl1, xr1, bias1, offs, csr, perm, h1);
  if (useBF)
    hipLaunchKernelGGL((linear2_kernel<true>), dim3(N_NODES / 16), dim3(256), 0, stream,
                       h1, Wl2, bl2, Wr2, br2, xl2, xr2);
  else
    hipLaunchKernelGGL((linear2_kernel<false>), dim3(N_NODES / 16), dim3(256), 0, stream,
                       h1, Wl2, bl2, Wr2, br2, xl2, xr2);
  hipLaunchKernelGGL(fused2_kernel, dim3(N_NODES / 8), dim3(512), 0, stream,
                     ea, srcs, We2, att2, xl2, xr2, bias2, offs, csr, h2);
  hipLaunchKernelGGL(head_kernel, dim3(N_NODES / 16), dim3(256), 0, stream,
                     h2, Wh1, bh1, Wh2, bh2, out);
}

// Round 10
// 595.854 us; speedup vs baseline: 1.5760x; 1.1195x over previous
//
#include <hip/hip_runtime.h>
#include <hip/hip_bf16.h>
#include <math.h>

#define N_NODES 20000
#define N_EDGES 320000
#define NODE_DIM 64
#define EDGE_DIM 32
#define HID 128
#define HEADS 4
#define HC1 512   // HEADS*HID
#define NEG_SLOPE 0.2f

__device__ __forceinline__ unsigned short f2b(float f) {
  unsigned u = __float_as_uint(f);
  unsigned r = (u + 0x7fffu + ((u >> 16) & 1u)) >> 16;
  return (unsigned short)r;
}
__device__ __forceinline__ float b2f(unsigned short b) {
  return __uint_as_float(((unsigned)b) << 16);
}

// ---------------- CSR build ----------------
__global__ void deg_count_kernel(const int* __restrict__ dsts, int* __restrict__ deg) {
  int e = blockIdx.x * blockDim.x + threadIdx.x;
  if (e < N_EDGES) atomicAdd(&deg[dsts[e]], 1);
}

__global__ __launch_bounds__(1024) void scan_kernel(
    const int* __restrict__ deg, int* __restrict__ offs, int* __restrict__ cursor)
{
  __shared__ int part[1024];
  int t = threadIdx.x;
  const int C = 20;                 // 1024*20 = 20480 >= N_NODES
  int base = t * C;
  int loc[C]; int s = 0;
  #pragma unroll
  for (int i = 0; i < C; i++) { loc[i] = s; int idx = base + i; s += (idx < N_NODES) ? deg[idx] : 0; }
  part[t] = s;
  __syncthreads();
  for (int off = 1; off < 1024; off <<= 1) {
    int v = (t >= off) ? part[t - off] : 0;
    __syncthreads();
    part[t] += v;
    __syncthreads();
  }
  int pbase = (t > 0) ? part[t - 1] : 0;
  #pragma unroll
  for (int i = 0; i < C; i++) {
    int idx = base + i;
    if (idx < N_NODES) { int o = pbase + loc[i]; offs[idx] = o; cursor[idx] = o; }
  }
  if (t == 1023) offs[N_NODES] = part[1023];
}

__global__ void scatter_kernel(const int* __restrict__ dsts, int* __restrict__ cursor,
                               int* __restrict__ csr) {
  int e = blockIdx.x * blockDim.x + threadIdx.x;
  if (e >= N_EDGES) return;
  int pos = atomicAdd(&cursor[dsts[e]], 1);
  csr[pos] = e;
}

// ---------------- linear1 ----------------
__global__ __launch_bounds__(256) void linear1_kernel(
    const float* __restrict__ x, const float* __restrict__ Wl,
    const float* __restrict__ bl, const float* __restrict__ Wr,
    const float* __restrict__ br, float* __restrict__ xl, float* __restrict__ xr)
{
  __shared__ float xsT[NODE_DIM][16];
  int n0 = blockIdx.x * 16;
  int t = threadIdx.x;
  {
    int flat = t * 4;
    int i = flat >> 6, k = flat & 63;
    float4 v = *(const float4*)&x[(size_t)(n0 + i) * NODE_DIM + k];
    xsT[k + 0][i] = v.x; xsT[k + 1][i] = v.y; xsT[k + 2][i] = v.z; xsT[k + 3][i] = v.w;
  }
  __syncthreads();
  for (int m = 0; m < 2; m++) {
    const float* W  = m ? Wr : Wl;
    const float* bb = m ? br : bl;
    float* out = m ? xr : xl;
    for (int jh = 0; jh < 2; jh++) {
      int j = t + jh * 256;
      float acc[16];
      #pragma unroll
      for (int i = 0; i < 16; i++) acc[i] = 0.f;
      for (int k = 0; k < NODE_DIM; k++) {
        float w = W[k * HC1 + j];
        float xv[16];
        *(float4*)&xv[0]  = *(const float4*)&xsT[k][0];
        *(float4*)&xv[4]  = *(const float4*)&xsT[k][4];
        *(float4*)&xv[8]  = *(const float4*)&xsT[k][8];
        *(float4*)&xv[12] = *(const float4*)&xsT[k][12];
        #pragma unroll
        for (int i = 0; i < 16; i++) acc[i] = fmaf(xv[i], w, acc[i]);
      }
      float bj = bb[j];
      #pragma unroll
      for (int i = 0; i < 16; i++) out[(size_t)(n0 + i) * HC1 + j] = acc[i] + bj;
    }
  }
}

// ---------------- fused layer 1 (half-split; gather-hoisted single xl read) ----------------
// block = 1024 threads = 16 waves = 16 nodes x ONE half (half = blockIdx&1).
// lane owns 4 channels: C = half*256 + lane*4; head = C>>7, 32-lane butterfly groups.
// GEMM acc starts at 0 (gather-independent); xl gathered ONCE, issued before GEMM.
template<bool H1BF>
__global__ __launch_bounds__(1024, 2) void fused1_kernel(
    const float* __restrict__ ea, const int* __restrict__ srcs,
    const float* __restrict__ We, const float* __restrict__ att,
    const float* __restrict__ xl, const float* __restrict__ xr,
    const float* __restrict__ bias, const int* __restrict__ offs,
    const int* __restrict__ csr, void* __restrict__ h1out)
{
  __shared__ float Ws[EDGE_DIM * 256];     // 32KB: this block's 256-col half of We
  __shared__ float eas[16][4][EDGE_DIM];   // 8KB, per-wave chunk ea tile
  int t = threadIdx.x;
  int half = blockIdx.x & 1;
  for (int i = t * 4; i < EDGE_DIM * 256; i += 4096) {
    int row = i >> 8, col = i & 255;
    *(float4*)&Ws[i] = *(const float4*)&We[(size_t)row * HC1 + half * 256 + col];
  }
  __syncthreads();
  int wave = t >> 6, lane = t & 63;
  int n = (blockIdx.x >> 1) * 16 + wave;   // 1250 groups * 16 = 20000 exact
  int Cl = lane * 4;                 // channel within the half
  int C = half * 256 + Cl;           // global channel
  float at4[4], xr4[4];
  *(float4*)at4 = *(const float4*)&att[C];
  *(float4*)xr4 = *(const float4*)&xr[(size_t)n * HC1 + C];
  float o4[4] = {0.f,0.f,0.f,0.f};
  float mx = 8.0f, dn = 0.f;        // shift-invariant base; defer-max rescale below
  int beg = offs[n], end = offs[n + 1];
  int ev = 0, sv = 0;
  if (lane < 4 && beg + lane < end) { ev = csr[beg + lane]; sv = srcs[ev]; }
  for (int i0 = beg; i0 < end; i0 += 4) {
    int nv = end - i0; if (nv > 4) nv = 4;
    int sarr[4];
    #pragma unroll
    for (int j = 0; j < 4; j++) sarr[j] = __shfl(sv, j);
    // issue xl gathers FIRST — latency hides under the whole GEMM below
    float xv0[4], xv1[4], xv2[4], xv3[4];
    #pragma unroll
    for (int c = 0; c < 4; c++) { xv0[c] = 0.f; xv1[c] = 0.f; xv2[c] = 0.f; xv3[c] = 0.f; }
    if (0 < nv) *(float4*)xv0 = *(const float4*)&xl[(size_t)sarr[0] * HC1 + C];
    if (1 < nv) *(float4*)xv1 = *(const float4*)&xl[(size_t)sarr[1] * HC1 + C];
    if (2 < nv) *(float4*)xv2 = *(const float4*)&xl[(size_t)sarr[2] * HC1 + C];
    if (3 < nv) *(float4*)xv3 = *(const float4*)&xl[(size_t)sarr[3] * HC1 + C];
    // stage this chunk's ea rows into per-wave LDS (coalesced float2/lane)
    {
      int mye = __shfl(ev, lane >> 4);
      float2 eav = *(const float2*)&ea[(size_t)mye * EDGE_DIM + (lane & 15) * 2];
      *(float2*)&eas[wave][lane >> 4][(lane & 15) * 2] = eav;
    }
    // prefetch next chunk's indices
    if (lane < 4 && i0 + 4 + lane < end) { ev = csr[i0 + 4 + lane]; sv = srcs[ev]; }
    // ee-GEMM (gather-independent): a4 = ea@We
    float a4[4][4];
    #pragma unroll
    for (int j = 0; j < 4; j++)
      #pragma unroll
      for (int c = 0; c < 4; c++) a4[j][c] = 0.f;
    #pragma unroll 1
    for (int kk = 0; kk < 8; kk++) {
      float w0[4], w1[4], w2[4], w3[4];
      *(float4*)w0 = *(const float4*)&Ws[(kk * 4 + 0) * 256 + Cl];
      *(float4*)w1 = *(const float4*)&Ws[(kk * 4 + 1) * 256 + Cl];
      *(float4*)w2 = *(const float4*)&Ws[(kk * 4 + 2) * 256 + Cl];
      *(float4*)w3 = *(const float4*)&Ws[(kk * 4 + 3) * 256 + Cl];
      #pragma unroll
      for (int j = 0; j < 4; j++) {
        float av[4];
        *(float4*)av = *(const float4*)&eas[wave][j][kk * 4];
        #pragma unroll
        for (int c = 0; c < 4; c++) {
          a4[j][c] = fmaf(av[0], w0[c], a4[j][c]);
          a4[j][c] = fmaf(av[1], w1[c], a4[j][c]);
          a4[j][c] = fmaf(av[2], w2[c], a4[j][c]);
          a4[j][c] = fmaf(av[3], w3[c], a4[j][c]);
        }
      }
    }
    // logits: z = a4 + xl + xr; leakyrelu + att dot; 32-lane (one head) butterflies
    float pl[4];
    #pragma unroll
    for (int j = 0; j < 4; j++) {
      const float* xvj = (j == 0) ? xv0 : (j == 1) ? xv1 : (j == 2) ? xv2 : xv3;
      float s = 0.f;
      #pragma unroll
      for (int c = 0; c < 4; c++) {
        float z = a4[j][c] + xvj[c] + xr4[c];
        float zm = z > 0.f ? z : NEG_SLOPE * z;
        s = fmaf(zm, at4[c], s);
      }
      #pragma unroll
      for (int o = 1; o <= 16; o <<= 1) s += __shfl_xor(s, o);
      pl[j] = (j < nv) ? s : -3.0e38f;
    }
    // defer-max online softmax
    float cm = fmaxf(fmaxf(pl[0], pl[1]), fmaxf(pl[2], pl[3]));
    float mn = fmaxf(mx, cm);
    if (__any(mn > mx + 8.f)) {
      float fs = __expf(mx - mn);
      dn *= fs;
      #pragma unroll
      for (int c = 0; c < 4; c++) o4[c] *= fs;
      mx = mn;
    }
    float p[4];
    #pragma unroll
    for (int j = 0; j < 4; j++) p[j] = __expf(pl[j] - mx);
    dn += (p[0] + p[1]) + (p[2] + p[3]);
    #pragma unroll
    for (int c = 0; c < 4; c++) {
      o4[c] += (p[0] * xv0[c] + p[1] * xv1[c]) + (p[2] * xv2[c] + p[3] * xv3[c]);
    }
  }
  float iv = dn > 0.f ? 1.f / dn : 0.f;
  float r[4];
  #pragma unroll
  for (int c = 0; c < 4; c++) {
    float v = o4[c] * iv + bias[C + c];
    r[c] = v > 0.f ? v : 0.f;            // relu after conv1
  }
  if (H1BF) {
    unsigned short* hb = (unsigned short*)h1out;
    ushort4 u;
    u.x = f2b(r[0]); u.y = f2b(r[1]); u.z = f2b(r[2]); u.w = f2b(r[3]);
    *(ushort4*)&hb[(size_t)n * HC1 + C] = u;
  } else {
    float* hf = (float*)h1out;
    *(float4*)&hf[(size_t)n * HC1 + C] = *(float4*)r;
  }
}

// ---------------- linear2 ----------------
template<bool INBF>
__global__ __launch_bounds__(256) void linear2_kernel(
    const void* __restrict__ hin_, const float* __restrict__ Wl,
    const float* __restrict__ bl, const float* __restrict__ Wr,
    const float* __restrict__ br, float* __restrict__ xl, float* __restrict__ xr)
{
  __shared__ float xsT[HC1][16];   // 32KB
  int n0 = blockIdx.x * 16;
  int t = threadIdx.x;
  for (int r = 0; r < 8; r++) {
    int flat = (t + r * 256) * 4;
    int i = flat >> 9, k = flat & 511;
    float4 v;
    if (INBF) {
      const unsigned short* hb = (const unsigned short*)hin_;
      ushort4 u = *(const ushort4*)&hb[(size_t)(n0 + i) * HC1 + k];
      v.x = b2f(u.x); v.y = b2f(u.y); v.z = b2f(u.z); v.w = b2f(u.w);
    } else {
      const float* hf = (const float*)hin_;
      v = *(const float4*)&hf[(size_t)(n0 + i) * HC1 + k];
    }
    xsT[k + 0][i] = v.x; xsT[k + 1][i] = v.y; xsT[k + 2][i] = v.z; xsT[k + 3][i] = v.w;
  }
  __syncthreads();
  int m = t >> 7, j = t & 127;
  const float* W = m ? Wr : Wl;
  float bj = (m ? br : bl)[j];
  float* out = m ? xr : xl;
  float acc[16];
  #pragma unroll
  for (int i = 0; i < 16; i++) acc[i] = 0.f;
  for (int k = 0; k < HC1; k++) {
    float w = W[k * HID + j];
    float xv[16];
    *(float4*)&xv[0]  = *(const float4*)&xsT[k][0];
    *(float4*)&xv[4]  = *(const float4*)&xsT[k][4];
    *(float4*)&xv[8]  = *(const float4*)&xsT[k][8];
    *(float4*)&xv[12] = *(const float4*)&xsT[k][12];
    #pragma unroll
    for (int i = 0; i < 16; i++) acc[i] = fmaf(xv[i], w, acc[i]);
  }
  #pragma unroll
  for (int i = 0; i < 16; i++) out[(size_t)(n0 + i) * HID + j] = acc[i] + bj;
}

// ---------------- fused layer 2 (consecutive channel pairs; eas-staged; chunk=8) ----------------
// block = 512 threads = 8 waves = 8 nodes. lane owns channels {2*lane, 2*lane+1}.
__global__ __launch_bounds__(512, 3) void fused2_kernel(
    const float* __restrict__ ea, const int* __restrict__ srcs,
    const float* __restrict__ We, const float* __restrict__ att,
    const float* __restrict__ xl, const float* __restrict__ xr,
    const float* __restrict__ bias, const int* __restrict__ offs,
    const int* __restrict__ csr, float* __restrict__ h2out)
{
  __shared__ float Ws[EDGE_DIM * HID];      // 16KB
  __shared__ float eas[8][8][EDGE_DIM];     // 8KB, per-wave chunk ea tile
  int t = threadIdx.x;
  for (int i = t * 4; i < EDGE_DIM * HID; i += 2048)
    *(float4*)&Ws[i] = *(const float4*)&We[i];
  __syncthreads();
  int wave = t >> 6, lane = t & 63;
  int n = blockIdx.x * 8 + wave;
  int c = lane * 2;
  float2 atv = *(const float2*)&att[c];
  float2 xrv = *(const float2*)&xr[(size_t)n * HID + c];
  float oa = 0.f, ob = 0.f;
  float m = 8.0f, d = 0.f;
  int beg = offs[n], end = offs[n + 1];
  int ev = 0, sv = 0;
  if (lane < 8 && beg + lane < end) { ev = csr[beg + lane]; sv = srcs[ev]; }
  for (int i0 = beg; i0 < end; i0 += 8) {
    int nv = end - i0; if (nv > 8) nv = 8;
    int sarr[8];
    #pragma unroll
    for (int j = 0; j < 8; j++) sarr[j] = __shfl(sv, j);
    // issue xl gathers first (float2, coalesced across lanes)
    float2 xv[8];
    #pragma unroll
    for (int j = 0; j < 8; j++) {
      if (j < nv) xv[j] = *(const float2*)&xl[(size_t)sarr[j] * HID + c];
      else { xv[j].x = 0.f; xv[j].y = 0.f; }
    }
    // stage this chunk's 8 ea rows into per-wave LDS (coalesced float4/lane)
    {
      int mye = __shfl(ev, lane >> 3);
      float4 eav = *(const float4*)&ea[(size_t)mye * EDGE_DIM + (lane & 7) * 4];
      *(float4*)&eas[wave][lane >> 3][(lane & 7) * 4] = eav;
    }
    // prefetch next chunk's indices
    if (lane < 8 && i0 + 8 + lane < end) { ev = csr[i0 + 8 + lane]; sv = srcs[ev]; }
    // ee-GEMM: LDS broadcast reads only
    float aa[8], ab[8];
    #pragma unroll
    for (int j = 0; j < 8; j++) { aa[j] = 0.f; ab[j] = 0.f; }
    #pragma unroll 2
    for (int kk = 0; kk < 8; kk++) {
      float av[8][4];
      #pragma unroll
      for (int j = 0; j < 8; j++)
        *(float4*)&av[j][0] = *(const float4*)&eas[wave][j][kk * 4];
      #pragma unroll
      for (int dk = 0; dk < 4; dk++) {
        float2 wv = *(const float2*)&Ws[(kk * 4 + dk) * HID + c];
        #pragma unroll
        for (int j = 0; j < 8; j++) {
          aa[j] = fmaf(av[j][dk], wv.x, aa[j]);
          ab[j] = fmaf(av[j][dk], wv.y, ab[j]);
        }
      }
    }
    // logits: 8 independent 64-lane butterflies
    float pl[8];
    #pragma unroll
    for (int j = 0; j < 8; j++) {
      float za = aa[j] + xv[j].x + xrv.x;
      float zb = ab[j] + xv[j].y + xrv.y;
      za = za > 0.f ? za : NEG_SLOPE * za;
      zb = zb > 0.f ? zb : NEG_SLOPE * zb;
      float s = za * atv.x + zb * atv.y;
      #pragma unroll
      for (int o = 1; o < 64; o <<= 1) s += __shfl_xor(s, o);
      pl[j] = (j < nv) ? s : -3.0e38f;
    }
    float cm = fmaxf(fmaxf(fmaxf(pl[0], pl[1]), fmaxf(pl[2], pl[3])),
                     fmaxf(fmaxf(pl[4], pl[5]), fmaxf(pl[6], pl[7])));
    float mn = fmaxf(m, cm);
    if (__any(mn > m + 8.f)) {
      float fs = __expf(m - mn);
      d *= fs; oa *= fs; ob *= fs;
      m = mn;
    }
    float p[8];
    #pragma unroll
    for (int j = 0; j < 8; j++) p[j] = __expf(pl[j] - m);
    d += ((p[0] + p[1]) + (p[2] + p[3])) + ((p[4] + p[5]) + (p[6] + p[7]));
    #pragma unroll
    for (int j = 0; j < 8; j++) {
      oa = fmaf(p[j], xv[j].x, oa);
      ob = fmaf(p[j], xv[j].y, ob);
    }
  }
  float invd = d > 0.f ? 1.f / d : 0.f;
  float2 o2 = make_float2(oa * invd + bias[c], ob * invd + bias[c + 1]); // no relu after conv2
  *(float2*)&h2out[(size_t)n * HID + c] = o2;
}

// ---------------- MLP head ----------------
__global__ __launch_bounds__(256) void head_kernel(
    const float* __restrict__ h2, const float* __restrict__ Wh1,
    const float* __restrict__ bh1, const float* __restrict__ Wh2,
    const float* __restrict__ bh2, float* __restrict__ out)
{
  __shared__ float hs[16][HID];   // 8KB
  __shared__ float ts[16][64];    // 4KB
  int n0 = blockIdx.x * 16;
  int t = threadIdx.x;
  for (int r = 0; r < 2; r++) {
    int flat = (t + r * 256) * 4; // 2048 floats
    int i = flat >> 7, k = flat & 127;
    *(float4*)&hs[i][k] = *(const float4*)&h2[(size_t)(n0 + i) * HID + k];
  }
  __syncthreads();
  int j = t & 63, g = t >> 6;
  float acc[4];
  #pragma unroll
  for (int q = 0; q < 4; q++) acc[q] = 0.f;
  for (int k = 0; k < HID; k++) {
    float w = Wh1[k * 64 + j];
    #pragma unroll
    for (int q = 0; q < 4; q++) acc[q] = fmaf(hs[g + 4 * q][k], w, acc[q]);
  }
  float bj = bh1[j];
  #pragma unroll
  for (int q = 0; q < 4; q++) {
    float v = acc[q] + bj;
    ts[g + 4 * q][j] = v > 0.f ? v : 0.f;
  }
  __syncthreads();
  if (t < 32) {
    int nl = t >> 1, k = t & 1;
    float acc2 = bh2[k];
    for (int jj = 0; jj < 64; jj++) acc2 = fmaf(ts[nl][jj], Wh2[jj * 2 + k], acc2);
    out[(size_t)(n0 + nl) * 2 + k] = acc2;
  }
}

extern "C" void kernel_launch(void* const* d_in, const int* in_sizes, int n_in,
                              void* d_out, int out_size, void* d_ws, size_t ws_size,
                              hipStream_t stream)
{
  (void)in_sizes; (void)n_in; (void)out_size;
  const float* x    = (const float*)d_in[0];
  const int* eidx   = (const int*)d_in[1];
  const float* ea   = (const float*)d_in[2];
  const float* Wl1  = (const float*)d_in[3];
  const float* bl1  = (const float*)d_in[4];
  const float* Wr1  = (const float*)d_in[5];
  const float* br1  = (const float*)d_in[6];
  const float* We1  = (const float*)d_in[7];
  const float* att1 = (const float*)d_in[8];
  const float* bias1= (const float*)d_in[9];
  const float* Wl2  = (const float*)d_in[10];
  const float* bl2  = (const float*)d_in[11];
  const float* Wr2  = (const float*)d_in[12];
  const float* br2  = (const float*)d_in[13];
  const float* We2  = (const float*)d_in[14];
  const float* att2 = (const float*)d_in[15];
  const float* bias2= (const float*)d_in[16];
  const float* Wh1  = (const float*)d_in[17];
  const float* bh1  = (const float*)d_in[18];
  const float* Wh2  = (const float*)d_in[19];
  const float* bh2  = (const float*)d_in[20];
  const int* srcs = eidx;
  const int* dsts = eidx + N_EDGES;
  float* out = (float*)d_out;

  const size_t szBig = (size_t)N_NODES * HC1 * sizeof(float);
  auto aln = [](size_t b) { return (b + 511) & ~(size_t)511; };
  size_t smallSz = aln((size_t)N_NODES * 4) * 2 + aln((size_t)(N_NODES + 1) * 4)
                 + aln((size_t)N_EDGES * 4);
  size_t needF = aln(szBig) * 3 + smallSz + 4096;
  bool useBF = ws_size < needF;

  char* p = (char*)d_ws;
  auto alloc = [&](size_t bytes) { char* q = p; p += (bytes + 511) & ~(size_t)511; return q; };
  float* xl1 = (float*)alloc(szBig);
  float* xr1 = (float*)alloc(szBig);          // reused for xl2/xr2 after fused1
  void*  h1  = (void*)alloc(useBF ? szBig / 2 : szBig);
  int* deg    = (int*)alloc((size_t)N_NODES * 4);
  int* offs   = (int*)alloc((size_t)(N_NODES + 1) * 4);
  int* cursor = (int*)alloc((size_t)N_NODES * 4);
  int* csr    = (int*)alloc((size_t)N_EDGES * 4);
  float* xl2 = xr1;
  float* xr2 = xr1 + (size_t)N_NODES * HID;
  float* h2  = xl1;                            // xl1 region dead after fused1

  hipMemsetAsync(deg, 0, (size_t)N_NODES * 4, stream);
  hipLaunchKernelGGL(deg_count_kernel, dim3((N_EDGES + 255) / 256), dim3(256), 0, stream, dsts, deg);
  hipLaunchKernelGGL(scan_kernel, dim3(1), dim3(1024), 0, stream, deg, offs, cursor);
  hipLaunchKernelGGL(scatter_kernel, dim3((N_EDGES + 255) / 256), dim3(256), 0, stream, dsts, cursor, csr);
  hipLaunchKernelGGL(linear1_kernel, dim3(N_NODES / 16), dim3(256), 0, stream,
                     x, Wl1, bl1, Wr1, br1, xl1, xr1);
  // fused1: grid = (N/16 node-groups) x 2 halves
  if (useBF)
    hipLaunchKernelGGL((fused1_kernel<true>), dim3((N_NODES / 16) * 2), dim3(1024), 0, stream,
                       ea, srcs, We1, att1, xl1, xr1, bias1, offs, csr, h1);
  else
    hipLaunchKernelGGL((fused1_kernel<false>), dim3((N_NODES / 16) * 2), dim3(1024), 0, stream,
                       ea, srcs, We1, att1, xl1, xr1, bias1, offs, csr, h1);
  if (useBF)
    hipLaunchKernelGGL((linear2_kernel<true>), dim3(N_NODES / 16), dim3(256), 0, stream,
                       h1, Wl2, bl2, Wr2, br2, xl2, xr2);
  else
    hipLaunchKernelGGL((linear2_kernel<false>), dim3(N_NODES / 16), dim3(256), 0, stream,
                       h1, Wl2, bl2, Wr2, br2, xl2, xr2);
  hipLaunchKernelGGL(fused2_kernel, dim3(N_NODES / 8), dim3(512), 0, stream,
                     ea, srcs, We2, att2, xl2, xr2, bias2, offs, csr, h2);
  hipLaunchKernelGGL(head_kernel, dim3(N_NODES / 16), dim3(256), 0, stream,
                     h2, Wh1, bh1, Wh2, bh2, out);
}